// Round 1
// baseline (320.457 us; speedup 1.0000x reference)
//
#include <hip/hip_runtime.h>

#define N 8192
#define M 8192
#define D 256

typedef unsigned short ushort_t;
typedef __attribute__((ext_vector_type(8))) short short8;
typedef __attribute__((ext_vector_type(4))) float floatx4;

__device__ __forceinline__ unsigned short f2bf(float f) {
  unsigned int u = __float_as_uint(f);
  u += 0x7fffu + ((u >> 16) & 1u);   // round-to-nearest-even
  return (unsigned short)(u >> 16);
}

// xb/sb hold the bf16 data in the EXACT LDS tile image the GEMM stages:
//   byte(r, k) = (r>>7)*65536                  // 128-row panel
//              + (k>>6)*16384                  // K-phase block (64 k-elems)
//              + (r&127)*128                   // row within panel (128 B)
//              + (((k>>3)&7) ^ (r&7))*16       // XOR-swizzled 16B slot (T2)
//              + (k&7)*2
// global_load_lds requires a LINEAR LDS destination (m104/m173), so the
// swizzle is baked into the workspace by prep; gemm staging is then a pure
// linear 1KB-per-inst tile memcpy and ds_read applies the same XOR ->
// conflict-free b128 fragment reads (was 8-way in the [row][32] layout).
__global__ __launch_bounds__(256) void prep_kernel(const float* __restrict__ x,
                                                   const float* __restrict__ s,
                                                   ushort_t* __restrict__ xb,
                                                   ushort_t* __restrict__ sb,
                                                   float* __restrict__ xn,
                                                   float* __restrict__ sn) {
  int gw = blockIdx.x * 4 + (threadIdx.x >> 6);
  int lane = threadIdx.x & 63;
  const float* src;
  ushort_t* dst;
  float* nrm;
  int row;
  if (gw < N) { src = x; dst = xb; nrm = xn; row = gw; }
  else        { src = s; dst = sb; nrm = sn; row = gw - N; }
  float4 v = ((const float4*)(src + (size_t)row * D))[lane];  // k = 4*lane..+3
  float ss = v.x * v.x + v.y * v.y + v.z * v.z + v.w * v.w;
  ushort4 o;
  o.x = f2bf(v.x); o.y = f2bf(v.y); o.z = f2bf(v.z); o.w = f2bf(v.w);
  int lr = row & 127;
  // kphase = lane>>4, slot = lane>>1 (8 elems/slot), half = lane&1
  size_t off = (size_t)(row >> 7) * 65536 + (size_t)(lane >> 4) * 16384
             + (size_t)lr * 128
             + (size_t)(((((lane >> 1) & 7) ^ (lr & 7)) * 16) + (lane & 1) * 8);
  *(ushort4*)((char*)dst + off) = o;
#pragma unroll
  for (int offs = 32; offs > 0; offs >>= 1) ss += __shfl_down(ss, offs);
  if (lane == 0) nrm[row] = ss;
}

// One compute phase: chunks 2P,2P+1 (k in [64P, 64P+64)).
template <int P>
__device__ __forceinline__ void phase_compute(const ushort_t* As, const ushort_t* Bs,
                                              floatx4 (&acc)[4][4], int wr, int wc,
                                              int q4, int m16) {
#pragma unroll
  for (int cc = 0; cc < 2; ++cc) {
    short8 a_frag[4], b_frag[4];
#pragma unroll
    for (int i = 0; i < 4; ++i) {
      const int row = wr + i * 16 + m16;
      a_frag[i] = *(const short8*)(As + P * 8192 + row * 64 +
                                   (((cc * 4 + q4) ^ (row & 7)) << 3));
    }
#pragma unroll
    for (int j = 0; j < 4; ++j) {
      const int row = wc + j * 16 + m16;
      b_frag[j] = *(const short8*)(Bs + P * 8192 + row * 64 +
                                   (((cc * 4 + q4) ^ (row & 7)) << 3));
    }
#pragma unroll
    for (int i = 0; i < 4; ++i)
#pragma unroll
      for (int j = 0; j < 4; ++j)
        acc[i][j] = __builtin_amdgcn_mfma_f32_16x16x32_bf16(a_frag[i], b_frag[j],
                                                            acc[i][j], 0, 0, 0);
  }
}

// 128x128 C-tile, 4 waves (2x2), full K=256 resident in LDS (129 KB -> 1
// block/CU). All 32 global_load_lds issued up-front in K-phase-major order;
// phases gated by COUNTED vmcnt (T4) + raw s_barrier -- no vmcnt(0) drain
// until the last phase, so loads for phases p+1.. stay in flight under the
// MFMAs of phase p.
__global__ __launch_bounds__(256, 1) void rbf_gemm(const ushort_t* __restrict__ X,
                                                   const ushort_t* __restrict__ S,
                                                   const float* __restrict__ xn,
                                                   const float* __restrict__ sn,
                                                   float* __restrict__ out) {
  __shared__ __attribute__((aligned(16))) ushort_t As[4 * 128 * 64];  // 64 KB
  __shared__ __attribute__((aligned(16))) ushort_t Bs[4 * 128 * 64];  // 64 KB
  __shared__ float nS[256];  // [0:128) row norms, [128:256) col norms

  const int tid = threadIdx.x;
  const int lane = tid & 63;
  const int wave = tid >> 6;

  // XCD-chunked bijective swizzle (T1): 4096 wgs, 8 XCDs, 512 contiguous each.
  const int wg = blockIdx.y * 64 + blockIdx.x;
  const int swz = (wg & 7) * 512 + (wg >> 3);
  const int by = swz >> 6;
  const int bx = swz & 63;

  // Norm load: exactly ONE vmem op per wave (branchless select), issued
  // BEFORE staging so it's the oldest vmcnt slot; the compiler drains it
  // before the ds_write (no staging in flight yet -> harmless).
  {
    const float* np = (tid < 128) ? (xn + by * 128 + tid)
                                  : (sn + bx * 128 + (tid - 128));
    nS[tid] = *np;
  }

  // Stage full A/B tiles: per wave 32 insts x 1 KB, phase p = insts [8p,8p+8).
  // Source layout == LDS layout (prep pre-tiled/pre-swizzled), so dest is the
  // same linear offset; HW adds lane*16 to the wave-uniform LDS base.
  const char* gA = (const char*)X + (size_t)by * 65536 + wave * 4096 + lane * 16;
  const char* gB = (const char*)S + (size_t)bx * 65536 + wave * 4096 + lane * 16;
  char* lA = (char*)As + wave * 4096;
  char* lB = (char*)Bs + wave * 4096;
#pragma unroll
  for (int p = 0; p < 4; ++p) {
#pragma unroll
    for (int i = 0; i < 4; ++i)
      __builtin_amdgcn_global_load_lds(
          (const __attribute__((address_space(1))) void*)(gA + p * 16384 + i * 1024),
          (__attribute__((address_space(3))) void*)(lA + p * 16384 + i * 1024), 16, 0, 0);
#pragma unroll
    for (int i = 0; i < 4; ++i)
      __builtin_amdgcn_global_load_lds(
          (const __attribute__((address_space(1))) void*)(gB + p * 16384 + i * 1024),
          (__attribute__((address_space(3))) void*)(lB + p * 16384 + i * 1024), 16, 0, 0);
  }

  const int wr = (wave >> 1) * 64;  // wave row offset in tile
  const int wc = (wave & 1) * 64;   // wave col offset in tile
  const int q4 = lane >> 4;
  const int m16 = lane & 15;

  floatx4 acc[4][4];
#pragma unroll
  for (int i = 0; i < 4; ++i)
#pragma unroll
    for (int j = 0; j < 4; ++j) acc[i][j] = (floatx4){0.f, 0.f, 0.f, 0.f};

  // Phase p: each wave waits its OWN loads for phase p (counted vmcnt), then
  // barrier => ALL waves' phase-p staging complete (identical issue counts).
  // asm "memory" clobber + sched_barrier(0) keep ds_reads below the gate.
  asm volatile("s_waitcnt vmcnt(24) lgkmcnt(0)" ::: "memory");  // + norm ds_write
  __builtin_amdgcn_s_barrier();
  __builtin_amdgcn_sched_barrier(0);
  phase_compute<0>(As, Bs, acc, wr, wc, q4, m16);

  asm volatile("s_waitcnt vmcnt(16)" ::: "memory");
  __builtin_amdgcn_s_barrier();
  __builtin_amdgcn_sched_barrier(0);
  phase_compute<1>(As, Bs, acc, wr, wc, q4, m16);

  asm volatile("s_waitcnt vmcnt(8)" ::: "memory");
  __builtin_amdgcn_s_barrier();
  __builtin_amdgcn_sched_barrier(0);
  phase_compute<2>(As, Bs, acc, wr, wc, q4, m16);

  asm volatile("s_waitcnt vmcnt(0)" ::: "memory");
  __builtin_amdgcn_s_barrier();
  __builtin_amdgcn_sched_barrier(0);
  phase_compute<3>(As, Bs, acc, wr, wc, q4, m16);

  // Epilogue: sq = ||x||^2 + ||s||^2 - 2*cross, clamped; out = exp(-sq/D).
  // C/D layout (m89/m91-verified): col = lane&15, row = (lane>>4)*4 + reg.
  const float cexp = -1.0f / (float)D;
#pragma unroll
  for (int i = 0; i < 4; ++i) {
#pragma unroll
    for (int j = 0; j < 4; ++j) {
#pragma unroll
      for (int r = 0; r < 4; ++r) {
        const int rl = wr + i * 16 + q4 * 4 + r;
        const int cl = wc + j * 16 + m16;
        float sq = nS[rl] + nS[128 + cl] - 2.0f * acc[i][j][r];
        sq = fmaxf(sq, 0.0f);
        out[(size_t)(by * 128 + rl) * M + (bx * 128 + cl)] = __expf(cexp * sq);
      }
    }
  }
}

extern "C" void kernel_launch(void* const* d_in, const int* in_sizes, int n_in,
                              void* d_out, int out_size, void* d_ws, size_t ws_size,
                              hipStream_t stream) {
  const float* x = (const float*)d_in[0];
  const float* s = (const float*)d_in[1];
  float* out = (float*)d_out;
  char* ws = (char*)d_ws;
  ushort_t* xb = (ushort_t*)ws;                           // 4 MB bf16 X (tiled+swz)
  ushort_t* sb = (ushort_t*)(ws + (size_t)N * D * 2);     // 4 MB bf16 S (tiled+swz)
  float* xn = (float*)(ws + (size_t)(N + M) * D * 2);     // 32 KB
  float* sn = xn + N;                                     // 32 KB

  prep_kernel<<<(N + M) / 4, 256, 0, stream>>>(x, s, xb, sb, xn, sn);
  dim3 grid(M / 128, N / 128);
  rbf_gemm<<<grid, 256, 0, stream>>>(xb, sb, xn, sn, out);
}

// Round 2
// 317.803 us; speedup vs baseline: 1.0084x; 1.0084x over previous
//
#include <hip/hip_runtime.h>

#define N 8192
#define M 8192
#define D 256

typedef unsigned short ushort_t;
typedef __attribute__((ext_vector_type(8))) short short8;
typedef __attribute__((ext_vector_type(4))) float floatx4;

__device__ __forceinline__ unsigned short f2bf(float f) {
  unsigned int u = __float_as_uint(f);
  u += 0x7fffu + ((u >> 16) & 1u);   // round-to-nearest-even
  return (unsigned short)(u >> 16);
}

// xb/sb hold the bf16 data in the EXACT LDS tile image the GEMM stages:
//   byte(r, k) = (r>>7)*65536                  // 128-row panel
//              + (k>>6)*16384                  // 64-k round block
//              + (r&127)*128                   // row within panel (128 B)
//              + (((k>>3)&7) ^ (r&7))*16       // XOR-swizzled 16B slot (T2)
//              + (k&7)*2
// global_load_lds needs a LINEAR LDS dest (m104/m173), so the swizzle is baked
// into the workspace here; gemm staging is then a pure linear 1KB-per-inst
// memcpy and the ds_read applies the same XOR -> ~2-way (free) bank access.
__global__ __launch_bounds__(256) void prep_kernel(const float* __restrict__ x,
                                                   const float* __restrict__ s,
                                                   ushort_t* __restrict__ xb,
                                                   ushort_t* __restrict__ sb,
                                                   float* __restrict__ xn,
                                                   float* __restrict__ sn) {
  int gw = blockIdx.x * 4 + (threadIdx.x >> 6);
  int lane = threadIdx.x & 63;
  const float* src;
  ushort_t* dst;
  float* nrm;
  int row;
  if (gw < N) { src = x; dst = xb; nrm = xn; row = gw; }
  else        { src = s; dst = sb; nrm = sn; row = gw - N; }
  float4 v = ((const float4*)(src + (size_t)row * D))[lane];  // k = 4*lane..+3
  float ss = v.x * v.x + v.y * v.y + v.z * v.z + v.w * v.w;
  ushort4 o;
  o.x = f2bf(v.x); o.y = f2bf(v.y); o.z = f2bf(v.z); o.w = f2bf(v.w);
  int lr = row & 127;
  size_t off = (size_t)(row >> 7) * 65536 + (size_t)(lane >> 4) * 16384
             + (size_t)lr * 128
             + (size_t)(((((lane >> 1) & 7) ^ (lr & 7)) * 16) + (lane & 1) * 8);
  *(ushort4*)((char*)dst + off) = o;
#pragma unroll
  for (int offs = 32; offs > 0; offs >>= 1) ss += __shfl_down(ss, offs);
  if (lane == 0) nrm[row] = ss;
}

// Compute one 64-k round from one LDS buffer pair (32 MFMA / wave).
__device__ __forceinline__ void compute_round(const ushort_t* __restrict__ As,
                                              const ushort_t* __restrict__ Bs,
                                              floatx4 (&acc)[4][4], int wr, int wc,
                                              int q4, int m16) {
#pragma unroll
  for (int cc = 0; cc < 2; ++cc) {
    short8 a_frag[4], b_frag[4];
#pragma unroll
    for (int i = 0; i < 4; ++i) {
      const int row = wr + i * 16 + m16;
      a_frag[i] = *(const short8*)(As + row * 64 + (((cc * 4 + q4) ^ (row & 7)) << 3));
    }
#pragma unroll
    for (int j = 0; j < 4; ++j) {
      const int row = wc + j * 16 + m16;
      b_frag[j] = *(const short8*)(Bs + row * 64 + (((cc * 4 + q4) ^ (row & 7)) << 3));
    }
#pragma unroll
    for (int i = 0; i < 4; ++i)
#pragma unroll
      for (int j = 0; j < 4; ++j)
        acc[i][j] = __builtin_amdgcn_mfma_f32_16x16x32_bf16(a_frag[i], b_frag[j],
                                                            acc[i][j], 0, 0, 0);
  }
}

// Stage one 64-k round: per wave 4 KB of A + 4 KB of B, 8 x 1KB insts.
__device__ __forceinline__ void stage_round(const char* gA, const char* gB,
                                            char* lA, char* lB) {
#pragma unroll
  for (int i = 0; i < 4; ++i)
    __builtin_amdgcn_global_load_lds(
        (const __attribute__((address_space(1))) void*)(gA + i * 1024),
        (__attribute__((address_space(3))) void*)(lA + i * 1024), 16, 0, 0);
#pragma unroll
  for (int i = 0; i < 4; ++i)
    __builtin_amdgcn_global_load_lds(
        (const __attribute__((address_space(1))) void*)(gB + i * 1024),
        (__attribute__((address_space(3))) void*)(lB + i * 1024), 16, 0, 0);
}

// 128x128 C-tile, 4 waves (2x2). BK=64, double-buffered LDS (64 KB total ->
// 2 blocks/CU, the m114 cross-block overlap that round-1's 129KB design lost)
// + counted-vmcnt round pipeline (T4: stage r+1 in flight under compute r,
// vmcnt never drains to 0 until the last round) + pre-swizzled conflict-free
// ds_reads (T2, baked by prep).
__global__ __launch_bounds__(256, 2) void rbf_gemm(const ushort_t* __restrict__ X,
                                                   const ushort_t* __restrict__ S,
                                                   const float* __restrict__ xn,
                                                   const float* __restrict__ sn,
                                                   float* __restrict__ out) {
  __shared__ __attribute__((aligned(16))) ushort_t As[2][128 * 64];  // 2 x 16 KB
  __shared__ __attribute__((aligned(16))) ushort_t Bs[2][128 * 64];  // 2 x 16 KB
  __shared__ float nS[256];  // [0:128) row norms, [128:256) col norms

  const int tid = threadIdx.x;
  const int lane = tid & 63;
  const int wave = tid >> 6;

  // XCD-chunked bijective swizzle (T1): 4096 wgs % 8 == 0, 512 contiguous/XCD.
  const int wg = blockIdx.y * 64 + blockIdx.x;
  const int swz = (wg & 7) * 512 + (wg >> 3);
  const int by = swz >> 6;
  const int bx = swz & 63;

  // Norm load: ONE vmem op per wave, fully drained (compiler vmcnt(0)) BEFORE
  // any staging issues, so the counted gates below see exact counts. The
  // sched_barrier pins it there.
  {
    const float* np = (tid < 128) ? (xn + by * 128 + tid)
                                  : (sn + bx * 128 + (tid - 128));
    nS[tid] = *np;
  }
  __builtin_amdgcn_sched_barrier(0);

  const char* gA = (const char*)X + (size_t)by * 65536 + wave * 4096 + lane * 16;
  const char* gB = (const char*)S + (size_t)bx * 65536 + wave * 4096 + lane * 16;
  char* lA0 = (char*)&As[0][0] + wave * 4096;
  char* lB0 = (char*)&Bs[0][0] + wave * 4096;
  char* lA1 = (char*)&As[1][0] + wave * 4096;
  char* lB1 = (char*)&Bs[1][0] + wave * 4096;

  const int wr = (wave >> 1) * 64;
  const int wc = (wave & 1) * 64;
  const int q4 = lane >> 4;
  const int m16 = lane & 15;

  floatx4 acc[4][4];
#pragma unroll
  for (int i = 0; i < 4; ++i)
#pragma unroll
    for (int j = 0; j < 4; ++j) acc[i][j] = (floatx4){0.f, 0.f, 0.f, 0.f};

  // S0 -> buf0
  stage_round(gA, gB, lA0, lB0);

  // ---- round 0: S1 -> buf1 in flight under compute(buf0)
  stage_round(gA + 16384, gB + 16384, lA1, lB1);
  asm volatile("s_waitcnt vmcnt(8) lgkmcnt(0)" ::: "memory");  // S0 done + nS write flushed
  __builtin_amdgcn_s_barrier();
  __builtin_amdgcn_sched_barrier(0);
  compute_round(As[0], Bs[0], acc, wr, wc, q4, m16);
  __builtin_amdgcn_s_barrier();  // all readers of buf0 done before S2 overwrites it

  // ---- round 1: S2 -> buf0 under compute(buf1)
  stage_round(gA + 2 * 16384, gB + 2 * 16384, lA0, lB0);
  asm volatile("s_waitcnt vmcnt(8)" ::: "memory");  // S1 done; S2 in flight
  __builtin_amdgcn_s_barrier();
  __builtin_amdgcn_sched_barrier(0);
  compute_round(As[1], Bs[1], acc, wr, wc, q4, m16);
  __builtin_amdgcn_s_barrier();  // readers of buf1 done before S3 overwrites it

  // ---- round 2: S3 -> buf1 under compute(buf0)
  stage_round(gA + 3 * 16384, gB + 3 * 16384, lA1, lB1);
  asm volatile("s_waitcnt vmcnt(8)" ::: "memory");  // S2 done; S3 in flight
  __builtin_amdgcn_s_barrier();
  __builtin_amdgcn_sched_barrier(0);
  compute_round(As[0], Bs[0], acc, wr, wc, q4, m16);

  // ---- round 3: nothing left to stage; only now drain to 0
  asm volatile("s_waitcnt vmcnt(0)" ::: "memory");
  __builtin_amdgcn_s_barrier();
  __builtin_amdgcn_sched_barrier(0);
  compute_round(As[1], Bs[1], acc, wr, wc, q4, m16);

  // Epilogue: sq = ||x||^2 + ||s||^2 - 2*cross, clamped; out = exp(-sq/D).
  // C/D layout (m89/m91-verified): col = lane&15, row = (lane>>4)*4 + reg.
  // Nontemporal: 256 MB streamed once, never re-read -> don't evict the
  // 8 MB input image from L2.
  const float cexp = -1.0f / (float)D;
#pragma unroll
  for (int i = 0; i < 4; ++i) {
#pragma unroll
    for (int j = 0; j < 4; ++j) {
#pragma unroll
      for (int r = 0; r < 4; ++r) {
        const int rl = wr + i * 16 + q4 * 4 + r;
        const int cl = wc + j * 16 + m16;
        float sq = nS[rl] + nS[128 + cl] - 2.0f * acc[i][j][r];
        sq = fmaxf(sq, 0.0f);
        __builtin_nontemporal_store(
            __expf(cexp * sq),
            out + (size_t)(by * 128 + rl) * M + (bx * 128 + cl));
      }
    }
  }
}

extern "C" void kernel_launch(void* const* d_in, const int* in_sizes, int n_in,
                              void* d_out, int out_size, void* d_ws, size_t ws_size,
                              hipStream_t stream) {
  const float* x = (const float*)d_in[0];
  const float* s = (const float*)d_in[1];
  float* out = (float*)d_out;
  char* ws = (char*)d_ws;
  ushort_t* xb = (ushort_t*)ws;                           // 4 MB bf16 X (tiled+swz)
  ushort_t* sb = (ushort_t*)(ws + (size_t)N * D * 2);     // 4 MB bf16 S (tiled+swz)
  float* xn = (float*)(ws + (size_t)(N + M) * D * 2);     // 32 KB
  float* sn = xn + N;                                     // 32 KB

  prep_kernel<<<(N + M) / 4, 256, 0, stream>>>(x, s, xb, sb, xn, sn);
  dim3 grid(M / 128, N / 128);
  rbf_gemm<<<grid, 256, 0, stream>>>(xb, sb, xn, sn, out);
}

// Round 3
// 302.786 us; speedup vs baseline: 1.0584x; 1.0496x over previous
//
#include <hip/hip_runtime.h>

#define N 8192
#define M 8192
#define D 256

typedef unsigned short ushort_t;
typedef __attribute__((ext_vector_type(8))) short short8;
typedef __attribute__((ext_vector_type(4))) float floatx4;

__device__ __forceinline__ unsigned short f2bf(float f) {
  unsigned int u = __float_as_uint(f);
  u += 0x7fffu + ((u >> 16) & 1u);   // round-to-nearest-even
  return (unsigned short)(u >> 16);
}

// xb/sb hold the bf16 data in the EXACT LDS tile image the GEMM stages
// (HW-verified correct in rounds 1-2: same absmax as the linear layout):
//   byte(r, k) = (r>>7)*65536                  // 128-row panel
//              + (k>>6)*16384                  // 64-k round block
//              + (r&127)*128                   // row within panel (128 B)
//              + (((k>>3)&7) ^ (r&7))*16       // XOR-swizzled 16B slot (T2)
//              + (k&7)*2
// global_load_lds needs a LINEAR LDS dest (m104/m173), so the swizzle is baked
// into the workspace here; gemm staging is a pure linear 1KB-per-inst memcpy
// and the ds_read applies the same XOR -> conflict-free b128 fragment reads
// (the old [row][32] layout was an 8-way conflict, ~2.9x per m136).
__global__ __launch_bounds__(256) void prep_kernel(const float* __restrict__ x,
                                                   const float* __restrict__ s,
                                                   ushort_t* __restrict__ xb,
                                                   ushort_t* __restrict__ sb,
                                                   float* __restrict__ xn,
                                                   float* __restrict__ sn) {
  int gw = blockIdx.x * 4 + (threadIdx.x >> 6);
  int lane = threadIdx.x & 63;
  const float* src;
  ushort_t* dst;
  float* nrm;
  int row;
  if (gw < N) { src = x; dst = xb; nrm = xn; row = gw; }
  else        { src = s; dst = sb; nrm = sn; row = gw - N; }
  float4 v = ((const float4*)(src + (size_t)row * D))[lane];  // k = 4*lane..+3
  float ss = v.x * v.x + v.y * v.y + v.z * v.z + v.w * v.w;
  ushort4 o;
  o.x = f2bf(v.x); o.y = f2bf(v.y); o.z = f2bf(v.z); o.w = f2bf(v.w);
  int lr = row & 127;
  size_t off = (size_t)(row >> 7) * 65536 + (size_t)(lane >> 4) * 16384
             + (size_t)lr * 128
             + (size_t)(((((lane >> 1) & 7) ^ (lr & 7)) * 16) + (lane & 1) * 8);
  *(ushort4*)((char*)dst + off) = o;
#pragma unroll
  for (int offs = 32; offs > 0; offs >>= 1) ss += __shfl_down(ss, offs);
  if (lane == 0) nrm[row] = ss;
}

// Compute one 64-k round from the LDS buffer (32 MFMA / wave).
__device__ __forceinline__ void compute_round(const ushort_t* __restrict__ As,
                                              const ushort_t* __restrict__ Bs,
                                              floatx4 (&acc)[4][4], int wr, int wc,
                                              int q4, int m16) {
#pragma unroll
  for (int cc = 0; cc < 2; ++cc) {
    short8 a_frag[4], b_frag[4];
#pragma unroll
    for (int i = 0; i < 4; ++i) {
      const int row = wr + i * 16 + m16;
      a_frag[i] = *(const short8*)(As + row * 64 + (((cc * 4 + q4) ^ (row & 7)) << 3));
    }
#pragma unroll
    for (int j = 0; j < 4; ++j) {
      const int row = wc + j * 16 + m16;
      b_frag[j] = *(const short8*)(Bs + row * 64 + (((cc * 4 + q4) ^ (row & 7)) << 3));
    }
#pragma unroll
    for (int i = 0; i < 4; ++i)
#pragma unroll
      for (int j = 0; j < 4; ++j)
        acc[i][j] = __builtin_amdgcn_mfma_f32_16x16x32_bf16(a_frag[i], b_frag[j],
                                                            acc[i][j], 0, 0, 0);
  }
}

// Stage one 64-k round: per wave 4 KB of A + 4 KB of B, 8 x 1KB insts.
__device__ __forceinline__ void stage_round(const char* gA, const char* gB,
                                            char* lA, char* lB) {
#pragma unroll
  for (int i = 0; i < 4; ++i)
    __builtin_amdgcn_global_load_lds(
        (const __attribute__((address_space(1))) void*)(gA + i * 1024),
        (__attribute__((address_space(3))) void*)(lA + i * 1024), 16, 0, 0);
#pragma unroll
  for (int i = 0; i < 4; ++i)
    __builtin_amdgcn_global_load_lds(
        (const __attribute__((address_space(1))) void*)(gB + i * 1024),
        (__attribute__((address_space(3))) void*)(lB + i * 1024), 16, 0, 0);
}

// 128x128 C-tile, 4 waves (2x2). Round-0 SCHEDULING (plain __syncthreads,
// compiler-scheduled, no inline asm / sched_barrier -- m141: order-pinning
// regresses) + BK=64 single-buffer: 32 KB LDS -> 3 blocks/CU (m132: the
// 64KB/2-block config loses ~40% vs this; cross-block m114 overlap hides the
// per-round vmcnt(0) drain) + T2 conflict-free fragment reads via the
// prep-baked swizzle (pure data layout, zero scheduling constructs).
__global__ __launch_bounds__(256, 3) void rbf_gemm(const ushort_t* __restrict__ X,
                                                   const ushort_t* __restrict__ S,
                                                   const float* __restrict__ xn,
                                                   const float* __restrict__ sn,
                                                   float* __restrict__ out) {
  __shared__ __attribute__((aligned(16))) ushort_t As[128 * 64];  // 16 KB
  __shared__ __attribute__((aligned(16))) ushort_t Bs[128 * 64];  // 16 KB
  __shared__ float nS[256];  // [0:128) row norms, [128:256) col norms

  const int tid = threadIdx.x;
  const int lane = tid & 63;
  const int wave = tid >> 6;
  const int bx = blockIdx.x;  // col block (support)
  const int by = blockIdx.y;  // row block (x)

  {
    const float* np = (tid < 128) ? (xn + by * 128 + tid)
                                  : (sn + bx * 128 + (tid - 128));
    nS[tid] = *np;
  }

  const char* gA = (const char*)X + (size_t)by * 65536 + wave * 4096 + lane * 16;
  const char* gB = (const char*)S + (size_t)bx * 65536 + wave * 4096 + lane * 16;
  char* lA = (char*)As + wave * 4096;
  char* lB = (char*)Bs + wave * 4096;

  const int wr = (wave >> 1) * 64;
  const int wc = (wave & 1) * 64;
  const int q4 = lane >> 4;
  const int m16 = lane & 15;

  floatx4 acc[4][4];
#pragma unroll
  for (int i = 0; i < 4; ++i)
#pragma unroll
    for (int j = 0; j < 4; ++j) acc[i][j] = (floatx4){0.f, 0.f, 0.f, 0.f};

#pragma unroll
  for (int r = 0; r < 4; ++r) {
    __syncthreads();  // previous round's readers done before overwrite
    stage_round(gA + r * 16384, gB + r * 16384, lA, lB);
    __syncthreads();  // compiler emits the vmcnt(0) drain before this barrier
    compute_round(As, Bs, acc, wr, wc, q4, m16);
  }

  // Epilogue: sq = ||x||^2 + ||s||^2 - 2*cross, clamped; out = exp(-sq/D).
  // C/D layout (m89/m91-verified): col = lane&15, row = (lane>>4)*4 + reg.
  // Nontemporal: 256 MB streamed once, never re-read -> keep inputs in L2.
  const float cexp = -1.0f / (float)D;
#pragma unroll
  for (int i = 0; i < 4; ++i) {
#pragma unroll
    for (int j = 0; j < 4; ++j) {
#pragma unroll
      for (int r = 0; r < 4; ++r) {
        const int rl = wr + i * 16 + q4 * 4 + r;
        const int cl = wc + j * 16 + m16;
        float sq = nS[rl] + nS[128 + cl] - 2.0f * acc[i][j][r];
        sq = fmaxf(sq, 0.0f);
        __builtin_nontemporal_store(
            __expf(cexp * sq),
            out + (size_t)(by * 128 + rl) * M + (bx * 128 + cl));
      }
    }
  }
}

extern "C" void kernel_launch(void* const* d_in, const int* in_sizes, int n_in,
                              void* d_out, int out_size, void* d_ws, size_t ws_size,
                              hipStream_t stream) {
  const float* x = (const float*)d_in[0];
  const float* s = (const float*)d_in[1];
  float* out = (float*)d_out;
  char* ws = (char*)d_ws;
  ushort_t* xb = (ushort_t*)ws;                           // 4 MB bf16 X (tiled+swz)
  ushort_t* sb = (ushort_t*)(ws + (size_t)N * D * 2);     // 4 MB bf16 S (tiled+swz)
  float* xn = (float*)(ws + (size_t)(N + M) * D * 2);     // 32 KB
  float* sn = xn + N;                                     // 32 KB

  prep_kernel<<<(N + M) / 4, 256, 0, stream>>>(x, s, xb, sb, xn, sn);
  dim3 grid(M / 128, N / 128);
  rbf_gemm<<<grid, 256, 0, stream>>>(xb, sb, xn, sn, out);
}